// Round 2
// baseline (160.861 us; speedup 1.0000x reference)
//
#include <hip/hip_runtime.h>

typedef unsigned short u16;
typedef unsigned int u32;
typedef unsigned long long u64;
using short8 = __attribute__((ext_vector_type(8))) short;
using f32x4  = __attribute__((ext_vector_type(4))) float;

#define NB 8
#define NN 2048

__device__ __forceinline__ u16 f2bf(float f) {
    u32 u = __float_as_uint(f);
    u32 r = (u + 0x7fffu + ((u >> 16) & 1u)) >> 16;   // RNE to bf16
    return (u16)r;
}
__device__ __forceinline__ float bf2f(u16 h) {
    return __uint_as_float(((u32)h) << 16);
}
// order-preserving float<->uint encoding for atomicMax
__device__ __forceinline__ u32 encf(float f) {
    u32 u = __float_as_uint(f);
    return (u & 0x80000000u) ? ~u : (u | 0x80000000u);
}
__device__ __forceinline__ float decf(u32 u) {
    return __uint_as_float((u & 0x80000000u) ? (u & 0x7fffffffu) : ~u);
}

// K12: h = x@W ; es/ed ; per-batch max(ed) ; hT hi/lo (transposed bf16 split) ;
//      PLUS adjacency bit-pack (coalesced streaming read of the 134 MB).
__global__ __launch_bounds__(256) void gat_k12(
    const float* __restrict__ x, const int* __restrict__ adj,
    const float* __restrict__ W, const float* __restrict__ a,
    u16* __restrict__ hT_hi, u16* __restrict__ hT_lo,
    float* __restrict__ es, float* __restrict__ ed,
    u32* __restrict__ edmax, u32* __restrict__ bits)
{
    const int tid  = threadIdx.x;
    const int lane = tid & 63;
    const int wid  = __builtin_amdgcn_readfirstlane(tid >> 6);
    const int rowbase = blockIdx.x * 16;          // global row in [0, B*N)
    const int row0 = rowbase + wid * 4;
    const int b    = rowbase >> 11;
    const int col0 = rowbase & 2047;

    float Wc[64];
#pragma unroll
    for (int k = 0; k < 64; ++k) Wc[k] = W[k * 64 + lane];
    const float asrc = a[lane], adst = a[64 + lane];

    __shared__ u16 lh[64][20];   // +4 pad
    __shared__ u16 ll[64][20];

    float edm = -1e30f;
#pragma unroll
    for (int r = 0; r < 4; ++r) {
        const float* xr = x + (size_t)(row0 + r) * 64;  // wave-uniform -> s_load
        float acc = 0.f;
#pragma unroll
        for (int k = 0; k < 64; ++k) acc = fmaf(xr[k], Wc[k], acc);
        float vs = acc * asrc, vd = acc * adst;
#pragma unroll
        for (int off = 32; off; off >>= 1) {
            vs += __shfl_xor(vs, off, 64);
            vd += __shfl_xor(vd, off, 64);
        }
        if (lane == 0) { es[row0 + r] = vs; ed[row0 + r] = vd; }
        edm = fmaxf(edm, vd);
        u16 hi = f2bf(acc);
        float lo = acc - bf2f(hi);
        lh[lane][wid * 4 + r] = hi;
        ll[lane][wid * 4 + r] = f2bf(lo);
    }
    if (lane == 0) atomicMax(edmax + b, encf(edm));
    __syncthreads();

    // transposed write-out: thread t -> d = t>>2, j-part = t&3 (4 bf16 = 8B)
    {
        const int d = tid >> 2, part = tid & 3;
        u32 h0 = lh[d][part*4+0] | ((u32)lh[d][part*4+1] << 16);
        u32 h1 = lh[d][part*4+2] | ((u32)lh[d][part*4+3] << 16);
        u32 l0 = ll[d][part*4+0] | ((u32)ll[d][part*4+1] << 16);
        u32 l1 = ll[d][part*4+2] | ((u32)ll[d][part*4+3] << 16);
        size_t goff = (size_t)(b * 64 + d) * 2048 + col0 + part * 4;
        *reinterpret_cast<uint2*>(hT_hi + goff) = make_uint2(h0, h1);
        *reinterpret_cast<uint2*>(hT_lo + goff) = make_uint2(l0, l1);
    }

    // adjacency bit-pack: wave handles 4 rows, coalesced 256B loads + ballot
#pragma unroll 1
    for (int r = 0; r < 4; ++r) {
        const int row = rowbase + (tid >> 6) * 4 + r;
        const int* __restrict__ arow = adj + (size_t)row * NN;
        u32* __restrict__ brow = bits + (size_t)row * 64;   // 2048 bits / row
#pragma unroll 8
        for (int seg = 0; seg < 32; ++seg) {                // 64 j per seg
            u64 m = __ballot(arow[seg * 64 + lane] != 0);
            if (lane == 0)
                *reinterpret_cast<u64*>(brow + seg * 2) = m;
        }
    }
}

// K3: fused masked-softmax + PV via MFMA, adjacency from register-resident bits.
// One block = 64 i-rows x full j-sweep; 16 waves = 4 row-groups x 4 j-chunks;
// chunk reduction in LDS (no global partials, no K4).
__global__ __launch_bounds__(1024) void gat_k3(
    const u32* __restrict__ bits,
    const u16* __restrict__ hT_hi, const u16* __restrict__ hT_lo,
    const float* __restrict__ es, const float* __restrict__ ed,
    const u32* __restrict__ edmax,
    float* __restrict__ out)
{
    const int g = blockIdx.x;
    const int b = g & 7;                  // batch pinned to XCD
    const int itile = g >> 3;             // 32 i-tiles of 64 rows per batch
    const int tid  = threadIdx.x;
    const int lane = tid & 63;
    const int w    = tid >> 6;            // wave 0..15
    const int rg   = w & 3;               // row-group
    const int c    = w >> 2;              // j-chunk 0..3 (512 cols each)
    const int li   = lane & 15;
    const int lg   = lane >> 4;
    const int i0   = itile * 64 + rg * 16;

    // adjacency bits for this lane's row & chunk: 512 bits = 4 x uint4
    const uint4* __restrict__ rb =
        reinterpret_cast<const uint4*>(bits + (size_t)(b * 2048 + i0 + li) * 64) + c * 4;
    uint4 vv[4];
    vv[0] = rb[0]; vv[1] = rb[1]; vv[2] = rb[2]; vv[3] = rb[3];

    const float es_i = es[b * 2048 + i0 + li];
    const float edM  = decf(edmax[b]);
    const float t0   = es_i + edM;
    const float Mi   = fmaxf(t0, 0.2f * t0);     // exact upper bound on row max
    const float L2E  = 1.44269504088896f;
    const float CL   = Mi * L2E;

    const float* __restrict__ edb = ed + b * 2048;
    const u16*   __restrict__ bh  = hT_hi + (size_t)(b * 64 + li) * 2048;
    const u16*   __restrict__ bl  = hT_lo + (size_t)(b * 64 + li) * 2048;

    f32x4 acc0 = {0.f,0.f,0.f,0.f}, acc1 = {0.f,0.f,0.f,0.f};
    f32x4 acc2 = {0.f,0.f,0.f,0.f}, acc3 = {0.f,0.f,0.f,0.f};
    float rs = 0.f;

#pragma unroll
    for (int t = 0; t < 4; ++t) {
        const uint4 vt = vv[t];
#pragma unroll
        for (int qq = 0; qq < 4; ++qq) {
            const int kk = t * 4 + qq;
            const u32 word = (qq == 0) ? vt.x : (qq == 1) ? vt.y : (qq == 2) ? vt.z : vt.w;
            const u32 byte = (word >> (lg * 8)) & 0xffu;   // this lane's 8 j-bits
            const int jo = c * 512 + kk * 32 + lg * 8;

            const float4 e0 = *reinterpret_cast<const float4*>(edb + jo);
            const float4 e1 = *reinterpret_cast<const float4*>(edb + jo + 4);
            const float ev[8] = {e0.x,e0.y,e0.z,e0.w,e1.x,e1.y,e1.z,e1.w};

            float pe[8];
#pragma unroll
            for (int q = 0; q < 8; ++q) {
                float tt = es_i + ev[q];
                float eL = fmaxf(tt, 0.2f * tt);
                float p  = __builtin_amdgcn_exp2f(fmaf(eL, L2E, -CL));
                pe[q] = ((byte >> q) & 1u) ? p : 0.f;
            }
            rs += ((pe[0]+pe[1]) + (pe[2]+pe[3])) + ((pe[4]+pe[5]) + (pe[6]+pe[7]));

            short8 pa;
#pragma unroll
            for (int q = 0; q < 8; ++q) pa[q] = (short)f2bf(pe[q]);

            short8 b0h = *reinterpret_cast<const short8*>(bh + (size_t)0*16*2048 + jo);
            short8 b1h = *reinterpret_cast<const short8*>(bh + (size_t)1*16*2048 + jo);
            short8 b2h = *reinterpret_cast<const short8*>(bh + (size_t)2*16*2048 + jo);
            short8 b3h = *reinterpret_cast<const short8*>(bh + (size_t)3*16*2048 + jo);
            short8 b0l = *reinterpret_cast<const short8*>(bl + (size_t)0*16*2048 + jo);
            short8 b1l = *reinterpret_cast<const short8*>(bl + (size_t)1*16*2048 + jo);
            short8 b2l = *reinterpret_cast<const short8*>(bl + (size_t)2*16*2048 + jo);
            short8 b3l = *reinterpret_cast<const short8*>(bl + (size_t)3*16*2048 + jo);

            acc0 = __builtin_amdgcn_mfma_f32_16x16x32_bf16(pa, b0h, acc0, 0, 0, 0);
            acc1 = __builtin_amdgcn_mfma_f32_16x16x32_bf16(pa, b1h, acc1, 0, 0, 0);
            acc2 = __builtin_amdgcn_mfma_f32_16x16x32_bf16(pa, b2h, acc2, 0, 0, 0);
            acc3 = __builtin_amdgcn_mfma_f32_16x16x32_bf16(pa, b3h, acc3, 0, 0, 0);
            acc0 = __builtin_amdgcn_mfma_f32_16x16x32_bf16(pa, b0l, acc0, 0, 0, 0);
            acc1 = __builtin_amdgcn_mfma_f32_16x16x32_bf16(pa, b1l, acc1, 0, 0, 0);
            acc2 = __builtin_amdgcn_mfma_f32_16x16x32_bf16(pa, b2l, acc2, 0, 0, 0);
            acc3 = __builtin_amdgcn_mfma_f32_16x16x32_bf16(pa, b3l, acc3, 0, 0, 0);
        }
    }

    // full per-row sum within this chunk: combine the 4 k-groups
    rs += __shfl_xor(rs, 16, 64);
    rs += __shfl_xor(rs, 32, 64);

    __shared__ float accL[16][16][64];   // [wave][row within 16][d]  64 KB
    __shared__ float rsL[4][64];         // [chunk][row within 64]

    if (lane < 16) rsL[c][rg * 16 + li] = rs;
    {
        f32x4 accs[4] = {acc0, acc1, acc2, acc3};
#pragma unroll
        for (int dt = 0; dt < 4; ++dt)
#pragma unroll
            for (int r = 0; r < 4; ++r)
                accL[w][4 * lg + r][dt * 16 + li] = accs[dt][r];
    }
    __syncthreads();

    // chunk-reduce + normalize + write: thread -> (row r = tid>>4, d0 = (tid&15)*4)
    {
        const int r  = tid >> 4;
        const int d0 = (tid & 15) * 4;
        const int rgo = r >> 4, ri = r & 15;
        const float s = (rsL[0][r] + rsL[1][r]) + (rsL[2][r] + rsL[3][r]);
        const float inv = 1.0f / s;
        float4 o;
        float* o4 = &o.x;
#pragma unroll
        for (int e = 0; e < 4; ++e) {
            float v = 0.f;
#pragma unroll
            for (int cc = 0; cc < 4; ++cc)
                v += accL[cc * 4 + rgo][ri][d0 + e];
            o4[e] = v * inv;
        }
        *reinterpret_cast<float4*>(out + ((size_t)(b * 2048 + itile * 64 + r) * 64 + d0)) = o;
    }
}

extern "C" void kernel_launch(void* const* d_in, const int* in_sizes, int n_in,
                              void* d_out, int out_size, void* d_ws, size_t ws_size,
                              hipStream_t stream)
{
    const float* x   = (const float*)d_in[0];
    const int*   adj = (const int*)d_in[1];
    const float* W   = (const float*)d_in[2];
    const float* a   = (const float*)d_in[3];
    float* out = (float*)d_out;

    char* ws = (char*)d_ws;
    size_t off = 0;
    auto carve = [&](size_t bytes) -> void* {
        void* p = ws + off;
        off += (bytes + 255) & ~(size_t)255;
        return p;
    };
    u16*   hT_hi = (u16*)  carve((size_t)NB * 64 * NN * 2);
    u16*   hT_lo = (u16*)  carve((size_t)NB * 64 * NN * 2);
    float* es    = (float*)carve((size_t)NB * NN * 4);
    float* ed    = (float*)carve((size_t)NB * NN * 4);
    u32*   edmax = (u32*)  carve(256);
    u32*   bits  = (u32*)  carve((size_t)NB * NN * 256);   // 2048 bits per row
    (void)ws_size; (void)in_sizes; (void)n_in; (void)out_size;

    hipMemsetAsync(edmax, 0, 256, stream);
    gat_k12<<<NB * NN / 16, 256, 0, stream>>>(x, adj, W, a, hT_hi, hT_lo, es, ed, edmax, bits);
    gat_k3<<<NB * NN / 64, 1024, 0, stream>>>(bits, hT_hi, hT_lo, es, ed, edmax, out);
}

// Round 3
// 151.393 us; speedup vs baseline: 1.0625x; 1.0625x over previous
//
#include <hip/hip_runtime.h>

typedef unsigned short u16;
typedef unsigned int u32;
typedef unsigned long long u64;
using short8 = __attribute__((ext_vector_type(8))) short;
using f32x4  = __attribute__((ext_vector_type(4))) float;

#define NB 8
#define NN 2048

__device__ __forceinline__ u16 f2bf(float f) {
    u32 u = __float_as_uint(f);
    u32 r = (u + 0x7fffu + ((u >> 16) & 1u)) >> 16;   // RNE to bf16
    return (u16)r;
}
__device__ __forceinline__ float bf2f(u16 h) {
    return __uint_as_float(((u32)h) << 16);
}
// order-preserving float<->uint encoding for atomicMax
__device__ __forceinline__ u32 encf(float f) {
    u32 u = __float_as_uint(f);
    return (u & 0x80000000u) ? ~u : (u | 0x80000000u);
}
__device__ __forceinline__ float decf(u32 u) {
    return __uint_as_float((u & 0x80000000u) ? (u & 0x7fffffffu) : ~u);
}

// K0: adjacency bit-pack. Branch-free, per-thread-contiguous 64 ints -> u64.
// 16 int4 loads all in flight before any consumption.
__global__ __launch_bounds__(256) void gat_k0(
    const int* __restrict__ adj, u32* __restrict__ bits)
{
    const size_t t0 = ((size_t)blockIdx.x * 256 + threadIdx.x) * 64; // int index
    const int4* __restrict__ p = reinterpret_cast<const int4*>(adj + t0);
    int4 v[16];
#pragma unroll
    for (int i = 0; i < 16; ++i) v[i] = p[i];
    u64 m = 0;
#pragma unroll
    for (int i = 0; i < 16; ++i) {
        m |= (u64)(v[i].x & 1) << (i * 4 + 0);
        m |= (u64)(v[i].y & 1) << (i * 4 + 1);
        m |= (u64)(v[i].z & 1) << (i * 4 + 2);
        m |= (u64)(v[i].w & 1) << (i * 4 + 3);
    }
    reinterpret_cast<u64*>(bits)[t0 >> 6] = m;
}

// K1: h = x@W ; es/ed ; per-batch max(ed) ; hT hi/lo (transposed bf16 split).
// x via LDS wave-uniform b128 broadcast; W columns in VGPRs.
__global__ __launch_bounds__(256, 2) void gat_k1(
    const float* __restrict__ x, const float* __restrict__ W, const float* __restrict__ a,
    u16* __restrict__ hT_hi, u16* __restrict__ hT_lo,
    float* __restrict__ es, float* __restrict__ ed, u32* __restrict__ edmax)
{
    const int tid  = threadIdx.x;
    const int lane = tid & 63;
    const int wid  = tid >> 6;
    const int rowbase = blockIdx.x * 16;          // global row in [0, B*N)
    const int b    = rowbase >> 11;
    const int col0 = rowbase & 2047;

    __shared__ float xs[16][64];   // 4 KB
    __shared__ u16 lh[64][20];     // +4 pad
    __shared__ u16 ll[64][20];

    // stage x tile coalesced: 256 threads x float4 = 4 KB
    {
        const float4 v = *reinterpret_cast<const float4*>(x + (size_t)rowbase * 64 + tid * 4);
        *reinterpret_cast<float4*>(&xs[0][0] + tid * 4) = v;
    }

    float Wc[64];
#pragma unroll
    for (int k = 0; k < 64; ++k) Wc[k] = W[k * 64 + lane];
    const float asrc = a[lane], adst = a[64 + lane];
    __syncthreads();

    float edm = -1e30f;
#pragma unroll
    for (int r = 0; r < 4; ++r) {
        const int row = wid * 4 + r;
        float acc = 0.f;
#pragma unroll
        for (int kq = 0; kq < 16; ++kq) {
            const float4 xv = *reinterpret_cast<const float4*>(&xs[row][kq * 4]); // broadcast
            acc = fmaf(xv.x, Wc[kq * 4 + 0], acc);
            acc = fmaf(xv.y, Wc[kq * 4 + 1], acc);
            acc = fmaf(xv.z, Wc[kq * 4 + 2], acc);
            acc = fmaf(xv.w, Wc[kq * 4 + 3], acc);
        }
        float vs = acc * asrc, vd = acc * adst;
#pragma unroll
        for (int off = 32; off; off >>= 1) {
            vs += __shfl_xor(vs, off, 64);
            vd += __shfl_xor(vd, off, 64);
        }
        if (lane == 0) { es[rowbase + row] = vs; ed[rowbase + row] = vd; }
        edm = fmaxf(edm, vd);
        u16 hi = f2bf(acc);
        float lo = acc - bf2f(hi);
        lh[lane][row] = hi;
        ll[lane][row] = f2bf(lo);
    }
    if (lane == 0) atomicMax(edmax + b, encf(edm));
    __syncthreads();

    // transposed write-out: thread t -> d = t>>2, j-part = t&3 (4 bf16 = 8B)
    {
        const int d = tid >> 2, part = tid & 3;
        u32 h0 = lh[d][part*4+0] | ((u32)lh[d][part*4+1] << 16);
        u32 h1 = lh[d][part*4+2] | ((u32)lh[d][part*4+3] << 16);
        u32 l0 = ll[d][part*4+0] | ((u32)ll[d][part*4+1] << 16);
        u32 l1 = ll[d][part*4+2] | ((u32)ll[d][part*4+3] << 16);
        size_t goff = (size_t)(b * 64 + d) * 2048 + col0 + part * 4;
        *reinterpret_cast<uint2*>(hT_hi + goff) = make_uint2(h0, h1);
        *reinterpret_cast<uint2*>(hT_lo + goff) = make_uint2(l0, l1);
    }
}

// K3: fused masked-softmax + PV via MFMA, adjacency from register-resident bits.
// One block = 64 i-rows x full j-sweep; 16 waves = 4 row-groups x 4 j-chunks;
// chunk reduction in LDS (no global partials).
__global__ __launch_bounds__(1024) void gat_k3(
    const u32* __restrict__ bits,
    const u16* __restrict__ hT_hi, const u16* __restrict__ hT_lo,
    const float* __restrict__ es, const float* __restrict__ ed,
    const u32* __restrict__ edmax,
    float* __restrict__ out)
{
    const int g = blockIdx.x;
    const int b = g & 7;                  // batch pinned to XCD
    const int itile = g >> 3;             // 32 i-tiles of 64 rows per batch
    const int tid  = threadIdx.x;
    const int lane = tid & 63;
    const int w    = tid >> 6;            // wave 0..15
    const int rg   = w & 3;               // row-group
    const int c    = w >> 2;              // j-chunk 0..3 (512 cols each)
    const int li   = lane & 15;
    const int lg   = lane >> 4;
    const int i0   = itile * 64 + rg * 16;

    // adjacency bits for this lane's row & chunk: 512 bits = 4 x uint4
    const uint4* __restrict__ rb =
        reinterpret_cast<const uint4*>(bits + (size_t)(b * 2048 + i0 + li) * 64) + c * 4;
    uint4 vv[4];
    vv[0] = rb[0]; vv[1] = rb[1]; vv[2] = rb[2]; vv[3] = rb[3];

    const float es_i = es[b * 2048 + i0 + li];
    const float edM  = decf(edmax[b]);
    const float t0   = es_i + edM;
    const float Mi   = fmaxf(t0, 0.2f * t0);     // exact upper bound on row max
    const float L2E  = 1.44269504088896f;
    const float CL   = Mi * L2E;

    const float* __restrict__ edb = ed + b * 2048;
    const u16*   __restrict__ bh  = hT_hi + (size_t)(b * 64 + li) * 2048;
    const u16*   __restrict__ bl  = hT_lo + (size_t)(b * 64 + li) * 2048;

    f32x4 acc0 = {0.f,0.f,0.f,0.f}, acc1 = {0.f,0.f,0.f,0.f};
    f32x4 acc2 = {0.f,0.f,0.f,0.f}, acc3 = {0.f,0.f,0.f,0.f};
    float rs = 0.f;

#pragma unroll
    for (int t = 0; t < 4; ++t) {
        const uint4 vt = vv[t];
#pragma unroll
        for (int qq = 0; qq < 4; ++qq) {
            const int kk = t * 4 + qq;
            const u32 word = (qq == 0) ? vt.x : (qq == 1) ? vt.y : (qq == 2) ? vt.z : vt.w;
            const u32 byte = (word >> (lg * 8)) & 0xffu;   // this lane's 8 j-bits
            const int jo = c * 512 + kk * 32 + lg * 8;

            const float4 e0 = *reinterpret_cast<const float4*>(edb + jo);
            const float4 e1 = *reinterpret_cast<const float4*>(edb + jo + 4);
            const float ev[8] = {e0.x,e0.y,e0.z,e0.w,e1.x,e1.y,e1.z,e1.w};

            float pe[8];
#pragma unroll
            for (int q = 0; q < 8; ++q) {
                float tt = es_i + ev[q];
                float eL = fmaxf(tt, 0.2f * tt);
                float p  = __builtin_amdgcn_exp2f(fmaf(eL, L2E, -CL));
                pe[q] = ((byte >> q) & 1u) ? p : 0.f;
            }
            rs += ((pe[0]+pe[1]) + (pe[2]+pe[3])) + ((pe[4]+pe[5]) + (pe[6]+pe[7]));

            short8 pa;
#pragma unroll
            for (int q = 0; q < 8; ++q) pa[q] = (short)f2bf(pe[q]);

            short8 b0h = *reinterpret_cast<const short8*>(bh + (size_t)0*16*2048 + jo);
            short8 b1h = *reinterpret_cast<const short8*>(bh + (size_t)1*16*2048 + jo);
            short8 b2h = *reinterpret_cast<const short8*>(bh + (size_t)2*16*2048 + jo);
            short8 b3h = *reinterpret_cast<const short8*>(bh + (size_t)3*16*2048 + jo);
            short8 b0l = *reinterpret_cast<const short8*>(bl + (size_t)0*16*2048 + jo);
            short8 b1l = *reinterpret_cast<const short8*>(bl + (size_t)1*16*2048 + jo);
            short8 b2l = *reinterpret_cast<const short8*>(bl + (size_t)2*16*2048 + jo);
            short8 b3l = *reinterpret_cast<const short8*>(bl + (size_t)3*16*2048 + jo);

            acc0 = __builtin_amdgcn_mfma_f32_16x16x32_bf16(pa, b0h, acc0, 0, 0, 0);
            acc1 = __builtin_amdgcn_mfma_f32_16x16x32_bf16(pa, b1h, acc1, 0, 0, 0);
            acc2 = __builtin_amdgcn_mfma_f32_16x16x32_bf16(pa, b2h, acc2, 0, 0, 0);
            acc3 = __builtin_amdgcn_mfma_f32_16x16x32_bf16(pa, b3h, acc3, 0, 0, 0);
            acc0 = __builtin_amdgcn_mfma_f32_16x16x32_bf16(pa, b0l, acc0, 0, 0, 0);
            acc1 = __builtin_amdgcn_mfma_f32_16x16x32_bf16(pa, b1l, acc1, 0, 0, 0);
            acc2 = __builtin_amdgcn_mfma_f32_16x16x32_bf16(pa, b2l, acc2, 0, 0, 0);
            acc3 = __builtin_amdgcn_mfma_f32_16x16x32_bf16(pa, b3l, acc3, 0, 0, 0);
        }
    }

    // full per-row sum within this chunk: combine the 4 k-groups
    rs += __shfl_xor(rs, 16, 64);
    rs += __shfl_xor(rs, 32, 64);

    __shared__ float accL[16][16][64];   // [wave][row within 16][d]  64 KB
    __shared__ float rsL[4][64];         // [chunk][row within 64]

    if (lane < 16) rsL[c][rg * 16 + li] = rs;
    {
        f32x4 accs[4] = {acc0, acc1, acc2, acc3};
#pragma unroll
        for (int dt = 0; dt < 4; ++dt)
#pragma unroll
            for (int r = 0; r < 4; ++r)
                accL[w][4 * lg + r][dt * 16 + li] = accs[dt][r];
    }
    __syncthreads();

    // chunk-reduce + normalize + write: thread -> (row r = tid>>4, d0 = (tid&15)*4)
    {
        const int r  = tid >> 4;
        const int d0 = (tid & 15) * 4;
        const int rgo = r >> 4, ri = r & 15;
        const float s = (rsL[0][r] + rsL[1][r]) + (rsL[2][r] + rsL[3][r]);
        const float inv = 1.0f / s;
        float4 o;
        float* o4 = &o.x;
#pragma unroll
        for (int e = 0; e < 4; ++e) {
            float v = 0.f;
#pragma unroll
            for (int cc = 0; cc < 4; ++cc)
                v += accL[cc * 4 + rgo][ri][d0 + e];
            o4[e] = v * inv;
        }
        *reinterpret_cast<float4*>(out + ((size_t)(b * 2048 + itile * 64 + r) * 64 + d0)) = o;
    }
}

extern "C" void kernel_launch(void* const* d_in, const int* in_sizes, int n_in,
                              void* d_out, int out_size, void* d_ws, size_t ws_size,
                              hipStream_t stream)
{
    const float* x   = (const float*)d_in[0];
    const int*   adj = (const int*)d_in[1];
    const float* W   = (const float*)d_in[2];
    const float* a   = (const float*)d_in[3];
    float* out = (float*)d_out;

    char* ws = (char*)d_ws;
    size_t off = 0;
    auto carve = [&](size_t bytes) -> void* {
        void* p = ws + off;
        off += (bytes + 255) & ~(size_t)255;
        return p;
    };
    u16*   hT_hi = (u16*)  carve((size_t)NB * 64 * NN * 2);
    u16*   hT_lo = (u16*)  carve((size_t)NB * 64 * NN * 2);
    float* es    = (float*)carve((size_t)NB * NN * 4);
    float* ed    = (float*)carve((size_t)NB * NN * 4);
    u32*   edmax = (u32*)  carve(256);
    u32*   bits  = (u32*)  carve((size_t)NB * NN * 256);   // 2048 bits per row
    (void)ws_size; (void)in_sizes; (void)n_in; (void)out_size;

    hipMemsetAsync(edmax, 0, 256, stream);
    gat_k0<<<(NB * (size_t)NN * NN) / (256 * 64), 256, 0, stream>>>(adj, bits);
    gat_k1<<<NB * NN / 16, 256, 0, stream>>>(x, W, a, hT_hi, hT_lo, es, ed, edmax);
    gat_k3<<<NB * NN / 64, 1024, 0, stream>>>(bits, hT_hi, hT_lo, es, ed, edmax, out);
}

// Round 4
// 145.414 us; speedup vs baseline: 1.1062x; 1.0411x over previous
//
#include <hip/hip_runtime.h>

typedef unsigned short u16;
typedef unsigned int u32;
typedef unsigned long long u64;
using short8 = __attribute__((ext_vector_type(8))) short;
using f32x4  = __attribute__((ext_vector_type(4))) float;

#define NB 8
#define NN 2048

__device__ __forceinline__ u16 f2bf(float f) {
    u32 u = __float_as_uint(f);
    u32 r = (u + 0x7fffu + ((u >> 16) & 1u)) >> 16;   // RNE to bf16
    return (u16)r;
}
__device__ __forceinline__ float bf2f(u16 h) {
    return __uint_as_float(((u32)h) << 16);
}
// order-preserving float<->uint encoding for atomicMax
__device__ __forceinline__ u32 encf(float f) {
    u32 u = __float_as_uint(f);
    return (u & 0x80000000u) ? ~u : (u | 0x80000000u);
}
__device__ __forceinline__ float decf(u32 u) {
    return __uint_as_float((u & 0x80000000u) ? (u & 0x7fffffffu) : ~u);
}
// pack low nibbles of 4 bytes -> 16 bits
__device__ __forceinline__ u32 nib4(u32 v) {
    u32 t = v & 0x0F0F0F0Fu;
    t = (t | (t >> 4)) & 0x00FF00FFu;
    t = (t | (t >> 8)) & 0x0000FFFFu;
    return t;
}

// K1: h = x@W ; es/ed ; per-batch max(ed) ; hT hi/lo (transposed bf16 split).
__global__ __launch_bounds__(256, 2) void gat_k1(
    const float* __restrict__ x, const float* __restrict__ W, const float* __restrict__ a,
    u16* __restrict__ hT_hi, u16* __restrict__ hT_lo,
    float* __restrict__ es, float* __restrict__ ed, u32* __restrict__ edmax)
{
    const int tid  = threadIdx.x;
    const int lane = tid & 63;
    const int wid  = tid >> 6;
    const int rowbase = blockIdx.x * 16;          // global row in [0, B*N)
    const int b    = rowbase >> 11;
    const int col0 = rowbase & 2047;

    __shared__ float xs[16][64];   // 4 KB
    __shared__ u16 lh[64][20];     // +4 pad
    __shared__ u16 ll[64][20];

    {
        const float4 v = *reinterpret_cast<const float4*>(x + (size_t)rowbase * 64 + tid * 4);
        *reinterpret_cast<float4*>(&xs[0][0] + tid * 4) = v;
    }

    float Wc[64];
#pragma unroll
    for (int k = 0; k < 64; ++k) Wc[k] = W[k * 64 + lane];
    const float asrc = a[lane], adst = a[64 + lane];
    __syncthreads();

    float edm = -1e30f;
#pragma unroll
    for (int r = 0; r < 4; ++r) {
        const int row = wid * 4 + r;
        float acc = 0.f;
#pragma unroll
        for (int kq = 0; kq < 16; ++kq) {
            const float4 xv = *reinterpret_cast<const float4*>(&xs[row][kq * 4]); // broadcast
            acc = fmaf(xv.x, Wc[kq * 4 + 0], acc);
            acc = fmaf(xv.y, Wc[kq * 4 + 1], acc);
            acc = fmaf(xv.z, Wc[kq * 4 + 2], acc);
            acc = fmaf(xv.w, Wc[kq * 4 + 3], acc);
        }
        float vs = acc * asrc, vd = acc * adst;
#pragma unroll
        for (int off = 32; off; off >>= 1) {
            vs += __shfl_xor(vs, off, 64);
            vd += __shfl_xor(vd, off, 64);
        }
        if (lane == 0) { es[rowbase + row] = vs; ed[rowbase + row] = vd; }
        edm = fmaxf(edm, vd);
        u16 hi = f2bf(acc);
        float lo = acc - bf2f(hi);
        lh[lane][row] = hi;
        ll[lane][row] = f2bf(lo);
    }
    if (lane == 0) atomicMax(edmax + b, encf(edm));
    __syncthreads();

    {
        const int d = tid >> 2, part = tid & 3;
        u32 h0 = lh[d][part*4+0] | ((u32)lh[d][part*4+1] << 16);
        u32 h1 = lh[d][part*4+2] | ((u32)lh[d][part*4+3] << 16);
        u32 l0 = ll[d][part*4+0] | ((u32)ll[d][part*4+1] << 16);
        u32 l1 = ll[d][part*4+2] | ((u32)ll[d][part*4+3] << 16);
        size_t goff = (size_t)(b * 64 + d) * 2048 + col0 + part * 4;
        *reinterpret_cast<uint2*>(hT_hi + goff) = make_uint2(h0, h1);
        *reinterpret_cast<uint2*>(hT_lo + goff) = make_uint2(l0, l1);
    }
}

// K3: fused {adjacency stage+bitpack in LDS} + masked-softmax + MFMA PV.
// Block = 32 i-rows x full j (2048); 8 waves = 2 row-groups x 4 j-chunks.
__global__ __launch_bounds__(512, 4) void gat_k3(
    const int* __restrict__ adj,
    const u16* __restrict__ hT_hi, const u16* __restrict__ hT_lo,
    const float* __restrict__ es, const float* __restrict__ ed,
    const u32* __restrict__ edmax,
    float* __restrict__ out)
{
    const int g = blockIdx.x;
    const int b = g & 7;                  // batch pinned to XCD
    const int itile = g >> 3;             // 64 i-tiles of 32 rows per batch
    const int i0b = itile * 32;
    const int tid  = threadIdx.x;
    const int lane = tid & 63;
    const int w    = tid >> 6;            // wave 0..7
    const int rg   = w >> 2;              // row-group 0..1
    const int c    = w & 3;               // j-chunk 0..3 (512 cols each)
    const int li   = lane & 15;
    const int lg   = lane >> 4;

    __shared__ unsigned char nib[16384];  // 16 KB: one nibble (as byte) per 4 cols
    __shared__ u64 bitsL[1024];           // 8 KB: [row][32 u64] bit mask
    __shared__ float accL[8][16][64];     // 32 KB
    __shared__ float rsL[4][32];

    // ---- Phase A: stage adjacency, fully coalesced int4 stream ----
    {
        const int4* __restrict__ base =
            reinterpret_cast<const int4*>(adj + ((size_t)(b * 2048 + i0b)) * 2048);
#pragma unroll 8
        for (int it = 0; it < 32; ++it) {
            const int idx = it * 512 + tid;
            const int4 v = base[idx];
            nib[idx] = (unsigned char)((v.x & 1) | ((v.y & 1) << 1) |
                                       ((v.z & 1) << 2) | ((v.w & 1) << 3));
        }
    }
    __syncthreads();

    // ---- Phase B: nibbles -> bit words ----
#pragma unroll
    for (int rep = 0; rep < 2; ++rep) {
        const int wd = rep * 512 + tid;           // u64 word index (row = wd>>5)
        const uint4 v = *reinterpret_cast<const uint4*>(nib + wd * 16);
        const u64 q0 = nib4(v.x), q1 = nib4(v.y), q2 = nib4(v.z), q3 = nib4(v.w);
        bitsL[wd] = q0 | (q1 << 16) | (q2 << 32) | (q3 << 48);
    }
    __syncthreads();

    // ---- adjacency bits for this lane's row & chunk: 512 bits = 4 x uint4 ----
    uint4 vv[4];
    {
        const unsigned char* bp = reinterpret_cast<const unsigned char*>(bitsL);
        const uint4* rb = reinterpret_cast<const uint4*>(bp + (rg * 16 + li) * 256 + c * 64);
        vv[0] = rb[0]; vv[1] = rb[1]; vv[2] = rb[2]; vv[3] = rb[3];
    }

    const float es_i = es[b * 2048 + i0b + rg * 16 + li];
    const float edM  = decf(edmax[b]);
    const float t0   = es_i + edM;
    const float Mi   = fmaxf(t0, 0.2f * t0);     // exact upper bound on row max
    const float L2E  = 1.44269504088896f;
    const float CL   = Mi * L2E;

    const float* __restrict__ edb = ed + b * 2048;
    const u16*   __restrict__ bh  = hT_hi + (size_t)(b * 64 + li) * 2048;
    const u16*   __restrict__ bl  = hT_lo + (size_t)(b * 64 + li) * 2048;

    f32x4 acc0 = {0.f,0.f,0.f,0.f}, acc1 = {0.f,0.f,0.f,0.f};
    f32x4 acc2 = {0.f,0.f,0.f,0.f}, acc3 = {0.f,0.f,0.f,0.f};
    float rs = 0.f;

#pragma unroll
    for (int t = 0; t < 4; ++t) {
        const uint4 vt = vv[t];
#pragma unroll
        for (int qq = 0; qq < 4; ++qq) {
            const int kk = t * 4 + qq;
            const u32 word = (qq == 0) ? vt.x : (qq == 1) ? vt.y : (qq == 2) ? vt.z : vt.w;
            const u32 byte = (word >> (lg * 8)) & 0xffu;   // this lane's 8 j-bits
            const int jo = c * 512 + kk * 32 + lg * 8;

            const float4 e0 = *reinterpret_cast<const float4*>(edb + jo);
            const float4 e1 = *reinterpret_cast<const float4*>(edb + jo + 4);
            const float ev[8] = {e0.x,e0.y,e0.z,e0.w,e1.x,e1.y,e1.z,e1.w};

            float pe[8];
#pragma unroll
            for (int q = 0; q < 8; ++q) {
                float tt = es_i + ev[q];
                float eL = fmaxf(tt, 0.2f * tt);
                float p  = __builtin_amdgcn_exp2f(fmaf(eL, L2E, -CL));
                pe[q] = ((byte >> q) & 1u) ? p : 0.f;
            }
            rs += ((pe[0]+pe[1]) + (pe[2]+pe[3])) + ((pe[4]+pe[5]) + (pe[6]+pe[7]));

            short8 pa;
#pragma unroll
            for (int q = 0; q < 8; ++q) pa[q] = (short)f2bf(pe[q]);

            short8 b0h = *reinterpret_cast<const short8*>(bh + (size_t)0*16*2048 + jo);
            short8 b1h = *reinterpret_cast<const short8*>(bh + (size_t)1*16*2048 + jo);
            short8 b2h = *reinterpret_cast<const short8*>(bh + (size_t)2*16*2048 + jo);
            short8 b3h = *reinterpret_cast<const short8*>(bh + (size_t)3*16*2048 + jo);
            short8 b0l = *reinterpret_cast<const short8*>(bl + (size_t)0*16*2048 + jo);
            short8 b1l = *reinterpret_cast<const short8*>(bl + (size_t)1*16*2048 + jo);
            short8 b2l = *reinterpret_cast<const short8*>(bl + (size_t)2*16*2048 + jo);
            short8 b3l = *reinterpret_cast<const short8*>(bl + (size_t)3*16*2048 + jo);

            acc0 = __builtin_amdgcn_mfma_f32_16x16x32_bf16(pa, b0h, acc0, 0, 0, 0);
            acc1 = __builtin_amdgcn_mfma_f32_16x16x32_bf16(pa, b1h, acc1, 0, 0, 0);
            acc2 = __builtin_amdgcn_mfma_f32_16x16x32_bf16(pa, b2h, acc2, 0, 0, 0);
            acc3 = __builtin_amdgcn_mfma_f32_16x16x32_bf16(pa, b3h, acc3, 0, 0, 0);
            acc0 = __builtin_amdgcn_mfma_f32_16x16x32_bf16(pa, b0l, acc0, 0, 0, 0);
            acc1 = __builtin_amdgcn_mfma_f32_16x16x32_bf16(pa, b1l, acc1, 0, 0, 0);
            acc2 = __builtin_amdgcn_mfma_f32_16x16x32_bf16(pa, b2l, acc2, 0, 0, 0);
            acc3 = __builtin_amdgcn_mfma_f32_16x16x32_bf16(pa, b3l, acc3, 0, 0, 0);
        }
    }

    // per-row sum within this chunk: combine the 4 k-groups
    rs += __shfl_xor(rs, 16, 64);
    rs += __shfl_xor(rs, 32, 64);

    if (lane < 16) rsL[c][rg * 16 + li] = rs;
    {
        f32x4 accs[4] = {acc0, acc1, acc2, acc3};
#pragma unroll
        for (int dt = 0; dt < 4; ++dt)
#pragma unroll
            for (int r = 0; r < 4; ++r)
                accL[w][4 * lg + r][dt * 16 + li] = accs[dt][r];
    }
    __syncthreads();

    // chunk-reduce + normalize + write: thread -> (row r = tid>>4, d0 = (tid&15)*4)
    {
        const int r  = tid >> 4;            // 0..31
        const int d0 = (tid & 15) * 4;
        const int rgo = r >> 4, ri = r & 15;
        const float s = (rsL[0][r] + rsL[1][r]) + (rsL[2][r] + rsL[3][r]);
        const float inv = 1.0f / s;
        float4 o;
        float* o4 = &o.x;
#pragma unroll
        for (int e = 0; e < 4; ++e) {
            float v = 0.f;
#pragma unroll
            for (int cc = 0; cc < 4; ++cc)
                v += accL[rgo * 4 + cc][ri][d0 + e];
            o4[e] = v * inv;
        }
        *reinterpret_cast<float4*>(out + ((size_t)(b * 2048 + i0b + r) * 64 + d0)) = o;
    }
}

extern "C" void kernel_launch(void* const* d_in, const int* in_sizes, int n_in,
                              void* d_out, int out_size, void* d_ws, size_t ws_size,
                              hipStream_t stream)
{
    const float* x   = (const float*)d_in[0];
    const int*   adj = (const int*)d_in[1];
    const float* W   = (const float*)d_in[2];
    const float* a   = (const float*)d_in[3];
    float* out = (float*)d_out;

    char* ws = (char*)d_ws;
    size_t off = 0;
    auto carve = [&](size_t bytes) -> void* {
        void* p = ws + off;
        off += (bytes + 255) & ~(size_t)255;
        return p;
    };
    u16*   hT_hi = (u16*)  carve((size_t)NB * 64 * NN * 2);
    u16*   hT_lo = (u16*)  carve((size_t)NB * 64 * NN * 2);
    float* es    = (float*)carve((size_t)NB * NN * 4);
    float* ed    = (float*)carve((size_t)NB * NN * 4);
    u32*   edmax = (u32*)  carve(256);
    (void)ws_size; (void)in_sizes; (void)n_in; (void)out_size;

    hipMemsetAsync(edmax, 0, 256, stream);
    gat_k1<<<NB * NN / 16, 256, 0, stream>>>(x, W, a, hT_hi, hT_lo, es, ed, edmax);
    gat_k3<<<NB * NN / 32, 512, 0, stream>>>(adj, hT_hi, hT_lo, es, ed, edmax, out);
}

// Round 5
// 105.686 us; speedup vs baseline: 1.5221x; 1.3759x over previous
//
#include <hip/hip_runtime.h>

typedef unsigned short u16;
typedef unsigned int u32;
typedef unsigned long long u64;
using short8 = __attribute__((ext_vector_type(8))) short;
using f32x4  = __attribute__((ext_vector_type(4))) float;

#define NB 8
#define NN 2048

// k3 LDS layout (bytes)
#define BITS_OFF  0        // u32[64 rows][32 words]            8192
#define EDL_OFF   8192     // float[1024]                       4096
#define RSL_OFF   12288    // float[2][64]                       512
#define DBUF_OFF  12800    // 2 bufs x 2 jq x (hi4K+lo4K)      32768
                           // aliases: PhaseA nibble scratch (16384), epilogue accL (32768)
#define SMEM_SZ   45568

__device__ __forceinline__ u16 f2bf(float f) {
    u32 u = __float_as_uint(f);
    u32 r = (u + 0x7fffu + ((u >> 16) & 1u)) >> 16;   // RNE to bf16
    return (u16)r;
}
__device__ __forceinline__ float bf2f(u16 h) {
    return __uint_as_float(((u32)h) << 16);
}
__device__ __forceinline__ u32 encf(float f) {
    u32 u = __float_as_uint(f);
    return (u & 0x80000000u) ? ~u : (u | 0x80000000u);
}
__device__ __forceinline__ float decf(u32 u) {
    return __uint_as_float((u & 0x80000000u) ? (u & 0x7fffffffu) : ~u);
}
// pack low nibbles of 4 bytes -> 16 bits
__device__ __forceinline__ u32 nib4(u32 v) {
    u32 t = v & 0x0F0F0F0Fu;
    t = (t | (t >> 4)) & 0x00FF00FFu;
    t = (t | (t >> 8)) & 0x0000FFFFu;
    return t;
}

// K1: h = x@W ; es/ed ; per-batch max(ed) ; hT hi/lo (transposed bf16 split).
__global__ __launch_bounds__(256, 2) void gat_k1(
    const float* __restrict__ x, const float* __restrict__ W, const float* __restrict__ a,
    u16* __restrict__ hT_hi, u16* __restrict__ hT_lo,
    float* __restrict__ es, float* __restrict__ ed, u32* __restrict__ edmax)
{
    const int tid  = threadIdx.x;
    const int lane = tid & 63;
    const int wid  = tid >> 6;
    const int rowbase = blockIdx.x * 16;          // global row in [0, B*N)
    const int b    = rowbase >> 11;
    const int col0 = rowbase & 2047;

    __shared__ float xs[16][64];
    __shared__ u16 lh[64][20];
    __shared__ u16 ll[64][20];

    {
        const float4 v = *reinterpret_cast<const float4*>(x + (size_t)rowbase * 64 + tid * 4);
        *reinterpret_cast<float4*>(&xs[0][0] + tid * 4) = v;
    }

    float Wc[64];
#pragma unroll
    for (int k = 0; k < 64; ++k) Wc[k] = W[k * 64 + lane];
    const float asrc = a[lane], adst = a[64 + lane];
    __syncthreads();

    float edm = -1e30f;
#pragma unroll
    for (int r = 0; r < 4; ++r) {
        const int row = wid * 4 + r;
        float acc = 0.f;
#pragma unroll
        for (int kq = 0; kq < 16; ++kq) {
            const float4 xv = *reinterpret_cast<const float4*>(&xs[row][kq * 4]);
            acc = fmaf(xv.x, Wc[kq * 4 + 0], acc);
            acc = fmaf(xv.y, Wc[kq * 4 + 1], acc);
            acc = fmaf(xv.z, Wc[kq * 4 + 2], acc);
            acc = fmaf(xv.w, Wc[kq * 4 + 3], acc);
        }
        float vs = acc * asrc, vd = acc * adst;
#pragma unroll
        for (int off = 32; off; off >>= 1) {
            vs += __shfl_xor(vs, off, 64);
            vd += __shfl_xor(vd, off, 64);
        }
        if (lane == 0) { es[rowbase + row] = vs; ed[rowbase + row] = vd; }
        edm = fmaxf(edm, vd);
        u16 hi = f2bf(acc);
        float lo = acc - bf2f(hi);
        lh[lane][row] = hi;
        ll[lane][row] = f2bf(lo);
    }
    if (lane == 0) atomicMax(edmax + b, encf(edm));
    __syncthreads();

    {
        const int d = tid >> 2, part = tid & 3;
        u32 h0 = lh[d][part*4+0] | ((u32)lh[d][part*4+1] << 16);
        u32 h1 = lh[d][part*4+2] | ((u32)lh[d][part*4+3] << 16);
        u32 l0 = ll[d][part*4+0] | ((u32)ll[d][part*4+1] << 16);
        u32 l1 = ll[d][part*4+2] | ((u32)ll[d][part*4+3] << 16);
        size_t goff = (size_t)(b * 64 + d) * 2048 + col0 + part * 4;
        *reinterpret_cast<uint2*>(hT_hi + goff) = make_uint2(h0, h1);
        *reinterpret_cast<uint2*>(hT_lo + goff) = make_uint2(l0, l1);
    }
}

// K3: block = 64 rows x 1024 j. 8 waves = 4 rg x 2 jq. LDS-fed MFMA pipeline.
__global__ __launch_bounds__(512, 4) void gat_k3(
    const int* __restrict__ adj,
    const u16* __restrict__ hT_hi, const u16* __restrict__ hT_lo,
    const float* __restrict__ es, const float* __restrict__ ed,
    const u32* __restrict__ edmax,
    float* __restrict__ acc_part, float* __restrict__ rs_part)
{
    __shared__ char smem[SMEM_SZ];
    const int g = blockIdx.x;
    const int b     = g & 7;              // batch -> XCD pinned
    const int t2    = g >> 3;
    const int itile = t2 & 31;            // 32 row-tiles of 64
    const int jhalf = t2 >> 5;            // 2 j-halves of 1024
    const int tid  = threadIdx.x;
    const int lane = tid & 63;
    const int w    = tid >> 6;            // 0..7
    const int rg   = w & 3;               // row-group (16 rows)
    const int jq   = w >> 2;              // j-quarter (512 cols)
    const int li   = lane & 15;
    const int lg   = lane >> 4;
    const int cb   = jhalf * 1024;        // col base
    const int gr0  = b * 2048 + itile * 64;  // global row base (0..16383)

    // ---- Phase A: adjacency slab -> nibble scratch (aliases dbuf); stage ed ----
    {
        unsigned char* scr = (unsigned char*)(smem + DBUF_OFF);
        const int4* abase = reinterpret_cast<const int4*>(adj + (size_t)gr0 * 2048 + cb);
#pragma unroll 8
        for (int it = 0; it < 32; ++it) {
            const int idx  = it * 512 + tid;      // 0..16383
            const int rrow = idx >> 8;            // 0..63
            const int grp  = idx & 255;           // int4 group within 1024-col half
            const int4 v = abase[rrow * 512 + grp];
            scr[idx] = (unsigned char)((v.x & 1) | ((v.y & 1) << 1) |
                                       ((v.z & 1) << 2) | ((v.w & 1) << 3));
        }
        float* edL = (float*)(smem + EDL_OFF);
        edL[tid]       = ed[b * 2048 + cb + tid];
        edL[tid + 512] = ed[b * 2048 + cb + tid + 512];
    }
    __syncthreads();

    // ---- Phase B: nibbles -> bit words (u32 per 32-col window) ----
    {
        const unsigned char* scr = (const unsigned char*)(smem + DBUF_OFF);
        u32* bw = (u32*)(smem + BITS_OFF);
#pragma unroll
        for (int rep = 0; rep < 4; ++rep) {
            const int wi = rep * 512 + tid;       // row*32 + word, 0..2047
            const uint2 nb = *reinterpret_cast<const uint2*>(scr + wi * 8);
            bw[wi] = nib4(nb.x) | (nib4(nb.y) << 16);
        }
    }
    __syncthreads();

    // ---- softmax constants ----
    const float es_i = es[gr0 + rg * 16 + li];
    const float edM  = decf(edmax[b]);
    const float t0   = es_i + edM;
    const float Mi   = fmaxf(t0, 0.2f * t0);      // exact upper bound on row max
    const float L2E  = 1.44269504088896f;
    const float CL   = Mi * L2E;

    // ---- staging geometry (reg -> LDS, T14 split) ----
    const int dd  = rg * 16 + (lane >> 2);        // d-row this lane stages
    const int sj8 = (lane & 3) * 8;               // j-offset within 32-col window
    const size_t gb = (size_t)(b * 64 + dd) * 2048 + cb + jq * 512 + sj8;
    const int swoff = dd * 64 + (lane & 3) * 16;  // LDS offset within slab

    // prologue: stage window 0 into buf0
    short8 svh = *reinterpret_cast<const short8*>(hT_hi + gb);
    short8 svl = *reinterpret_cast<const short8*>(hT_lo + gb);
    {
        char* slab = smem + DBUF_OFF + jq * 8192;
        *reinterpret_cast<short8*>(slab + swoff) = svh;
        *reinterpret_cast<short8*>(slab + 4096 + swoff) = svl;
    }
    __syncthreads();

    f32x4 acc0 = {0.f,0.f,0.f,0.f}, acc1 = {0.f,0.f,0.f,0.f};
    f32x4 acc2 = {0.f,0.f,0.f,0.f}, acc3 = {0.f,0.f,0.f,0.f};
    float rs = 0.f;
    uint4 bw4 = {0,0,0,0};

    const float* edq = (const float*)(smem + EDL_OFF) + jq * 512 + lg * 8;
    const int bitrow = (rg * 16 + li) * 32 + jq * 16;
    const int fo = li * 64 + lg * 16;
    char* slabA = smem + DBUF_OFF + jq * 8192;            // buf 0
    char* slabB = smem + DBUF_OFF + (2 + jq) * 8192;      // buf 1

#pragma unroll 2
    for (int kk = 0; kk < 16; ++kk) {
        // issue next window's global loads early (hide L2 latency under compute)
        if (kk < 15) {
            svh = *reinterpret_cast<const short8*>(hT_hi + gb + (kk + 1) * 32);
            svl = *reinterpret_cast<const short8*>(hT_lo + gb + (kk + 1) * 32);
        }
        if ((kk & 3) == 0)
            bw4 = *reinterpret_cast<const uint4*>((const u32*)(smem + BITS_OFF) + bitrow + kk);
        const u32 word = ((kk & 3) == 0) ? bw4.x : ((kk & 3) == 1) ? bw4.y
                        : ((kk & 3) == 2) ? bw4.z : bw4.w;
        const u32 byt = (word >> (lg * 8)) & 0xffu;

        const float4 e0 = *reinterpret_cast<const float4*>(edq + kk * 32);
        const float4 e1 = *reinterpret_cast<const float4*>(edq + kk * 32 + 4);
        const float ev[8] = {e0.x,e0.y,e0.z,e0.w,e1.x,e1.y,e1.z,e1.w};

        float pe[8];
#pragma unroll
        for (int q = 0; q < 8; ++q) {
            const float tt = es_i + ev[q];
            const float eL = fmaxf(tt, 0.2f * tt);
            const float p  = __builtin_amdgcn_exp2f(fmaf(eL, L2E, -CL));
            pe[q] = ((byt >> q) & 1u) ? p : 0.f;
        }
        rs += ((pe[0]+pe[1]) + (pe[2]+pe[3])) + ((pe[4]+pe[5]) + (pe[6]+pe[7]));

        short8 pa;
#pragma unroll
        for (int q = 0; q < 8; ++q) pa[q] = (short)f2bf(pe[q]);

        const char* slab = (kk & 1) ? slabB : slabA;
        short8 f0h = *reinterpret_cast<const short8*>(slab + fo);
        short8 f1h = *reinterpret_cast<const short8*>(slab + 1024 + fo);
        short8 f2h = *reinterpret_cast<const short8*>(slab + 2048 + fo);
        short8 f3h = *reinterpret_cast<const short8*>(slab + 3072 + fo);
        short8 f0l = *reinterpret_cast<const short8*>(slab + 4096 + fo);
        short8 f1l = *reinterpret_cast<const short8*>(slab + 5120 + fo);
        short8 f2l = *reinterpret_cast<const short8*>(slab + 6144 + fo);
        short8 f3l = *reinterpret_cast<const short8*>(slab + 7168 + fo);

        acc0 = __builtin_amdgcn_mfma_f32_16x16x32_bf16(pa, f0h, acc0, 0, 0, 0);
        acc1 = __builtin_amdgcn_mfma_f32_16x16x32_bf16(pa, f1h, acc1, 0, 0, 0);
        acc2 = __builtin_amdgcn_mfma_f32_16x16x32_bf16(pa, f2h, acc2, 0, 0, 0);
        acc3 = __builtin_amdgcn_mfma_f32_16x16x32_bf16(pa, f3h, acc3, 0, 0, 0);
        acc0 = __builtin_amdgcn_mfma_f32_16x16x32_bf16(pa, f0l, acc0, 0, 0, 0);
        acc1 = __builtin_amdgcn_mfma_f32_16x16x32_bf16(pa, f1l, acc1, 0, 0, 0);
        acc2 = __builtin_amdgcn_mfma_f32_16x16x32_bf16(pa, f2l, acc2, 0, 0, 0);
        acc3 = __builtin_amdgcn_mfma_f32_16x16x32_bf16(pa, f3l, acc3, 0, 0, 0);

        // write staged regs into the other buffer (WAR-safe: its readers drained
        // at the previous barrier)
        if (kk < 15) {
            char* nslab = (kk & 1) ? slabA : slabB;
            *reinterpret_cast<short8*>(nslab + swoff) = svh;
            *reinterpret_cast<short8*>(nslab + 4096 + swoff) = svl;
        }
        __syncthreads();
    }

    // ---- epilogue: jq-combine in LDS, write per-jhalf partials ----
    rs += __shfl_xor(rs, 16, 64);
    rs += __shfl_xor(rs, 32, 64);
    float* rsL = (float*)(smem + RSL_OFF);
    if (lane < 16) rsL[jq * 64 + rg * 16 + li] = rs;

    float* accL = (float*)(smem + DBUF_OFF);   // [w][16][64], aliases dbuf (reads drained)
    {
        f32x4 accs[4] = {acc0, acc1, acc2, acc3};
#pragma unroll
        for (int dt = 0; dt < 4; ++dt)
#pragma unroll
            for (int r = 0; r < 4; ++r)
                accL[(w * 16 + 4 * lg + r) * 64 + dt * 16 + li] = accs[dt][r];
    }
    __syncthreads();

    {
#pragma unroll
        for (int rep = 0; rep < 2; ++rep) {
            const int fi = (rep * 512 + tid) * 4;       // float idx 0..4095
            const int r  = fi >> 6;                     // row 0..63
            const int d0 = fi & 63;
            const int rgo = r >> 4, ri = r & 15;
            const float4 u0 = *reinterpret_cast<const float4*>(accL + ((0 + rgo) * 16 + ri) * 64 + d0);
            const float4 u1 = *reinterpret_cast<const float4*>(accL + ((4 + rgo) * 16 + ri) * 64 + d0);
            float4 o = make_float4(u0.x+u1.x, u0.y+u1.y, u0.z+u1.z, u0.w+u1.w);
            *reinterpret_cast<float4*>(acc_part + ((size_t)jhalf * 16384 + gr0 + r) * 64 + d0) = o;
        }
        if (tid < 64)
            rs_part[(size_t)jhalf * 16384 + gr0 + tid] = rsL[tid] + rsL[64 + tid];
    }
}

// K4: combine the two j-halves, normalize
__global__ __launch_bounds__(512) void gat_k4(
    const float4* __restrict__ ap, const float* __restrict__ rp,
    float4* __restrict__ out)
{
    const int idx = blockIdx.x * 512 + threadIdx.x;   // 0..262143 float4s
    const int row = idx >> 4;
    const float4 u0 = ap[idx];
    const float4 u1 = ap[262144 + idx];
    const float inv = 1.0f / (rp[row] + rp[16384 + row]);
    out[idx] = make_float4((u0.x+u1.x)*inv, (u0.y+u1.y)*inv,
                           (u0.z+u1.z)*inv, (u0.w+u1.w)*inv);
}

extern "C" void kernel_launch(void* const* d_in, const int* in_sizes, int n_in,
                              void* d_out, int out_size, void* d_ws, size_t ws_size,
                              hipStream_t stream)
{
    const float* x   = (const float*)d_in[0];
    const int*   adj = (const int*)d_in[1];
    const float* W   = (const float*)d_in[2];
    const float* a   = (const float*)d_in[3];
    float* out = (float*)d_out;

    char* ws = (char*)d_ws;
    size_t off = 0;
    auto carve = [&](size_t bytes) -> void* {
        void* p = ws + off;
        off += (bytes + 255) & ~(size_t)255;
        return p;
    };
    u16*   hT_hi    = (u16*)  carve((size_t)NB * 64 * NN * 2);
    u16*   hT_lo    = (u16*)  carve((size_t)NB * 64 * NN * 2);
    float* es       = (float*)carve((size_t)NB * NN * 4);
    float* ed       = (float*)carve((size_t)NB * NN * 4);
    u32*   edmax    = (u32*)  carve(256);
    float* acc_part = (float*)carve((size_t)2 * NB * NN * 64 * 4);  // 8 MB
    float* rs_part  = (float*)carve((size_t)2 * NB * NN * 4);       // 128 KB
    (void)ws_size; (void)in_sizes; (void)n_in; (void)out_size;

    hipMemsetAsync(edmax, 0, 256, stream);
    gat_k1<<<NB * NN / 16, 256, 0, stream>>>(x, W, a, hT_hi, hT_lo, es, ed, edmax);
    gat_k3<<<2 * NB * NN / 64, 512, 0, stream>>>(adj, hT_hi, hT_lo, es, ed, edmax,
                                                 acc_part, rs_part);
    gat_k4<<<512, 512, 0, stream>>>((const float4*)acc_part, rs_part, (float4*)out);
}

// Round 6
// 92.641 us; speedup vs baseline: 1.7364x; 1.1408x over previous
//
#include <hip/hip_runtime.h>

typedef unsigned short u16;
typedef unsigned int u32;
typedef unsigned long long u64;
using short8 = __attribute__((ext_vector_type(8))) short;
using f32x4  = __attribute__((ext_vector_type(4))) float;

#define NB 8
#define NN 2048

// k3 LDS layout (bytes)
#define EDL_OFF   0        // float[1024]                              4096
#define RSL_OFF   4096     // float[2][64]                              512
#define DBUF_OFF  4608     // 2 bufs x 2 jq x (hi 64*80 + lo 64*80) = 40960
                           // alias: epilogue accL (32768)
#define SLAB_SZ   10240    // per (buf,jq): hi 5120 + lo 5120
#define ROWB      80       // LDS row stride in bytes (5x16B -> 2-way max)
#define SMEM_SZ   45568

__device__ __forceinline__ u16 f2bf(float f) {
    u32 u = __float_as_uint(f);
    u32 r = (u + 0x7fffu + ((u >> 16) & 1u)) >> 16;   // RNE to bf16
    return (u16)r;
}
__device__ __forceinline__ float bf2f(u16 h) {
    return __uint_as_float(((u32)h) << 16);
}
__device__ __forceinline__ u32 encf(float f) {
    u32 u = __float_as_uint(f);
    return (u & 0x80000000u) ? ~u : (u | 0x80000000u);
}
__device__ __forceinline__ float decf(u32 u) {
    return __uint_as_float((u & 0x80000000u) ? (u & 0x7fffffffu) : ~u);
}

// K1: h = x@W ; es/ed ; per-batch max(ed) ; hT hi/lo (transposed bf16 split).
__global__ __launch_bounds__(256, 2) void gat_k1(
    const float* __restrict__ x, const float* __restrict__ W, const float* __restrict__ a,
    u16* __restrict__ hT_hi, u16* __restrict__ hT_lo,
    float* __restrict__ es, float* __restrict__ ed, u32* __restrict__ edmax)
{
    const int tid  = threadIdx.x;
    const int lane = tid & 63;
    const int wid  = tid >> 6;
    const int rowbase = blockIdx.x * 16;          // global row in [0, B*N)
    const int b    = rowbase >> 11;
    const int col0 = rowbase & 2047;

    __shared__ float xs[16][64];
    __shared__ u16 lh[64][20];
    __shared__ u16 ll[64][20];

    {
        const float4 v = *reinterpret_cast<const float4*>(x + (size_t)rowbase * 64 + tid * 4);
        *reinterpret_cast<float4*>(&xs[0][0] + tid * 4) = v;
    }

    float Wc[64];
#pragma unroll
    for (int k = 0; k < 64; ++k) Wc[k] = W[k * 64 + lane];
    const float asrc = a[lane], adst = a[64 + lane];
    __syncthreads();

    float edm = -1e30f;
#pragma unroll
    for (int r = 0; r < 4; ++r) {
        const int row = wid * 4 + r;
        float acc = 0.f;
#pragma unroll
        for (int kq = 0; kq < 16; ++kq) {
            const float4 xv = *reinterpret_cast<const float4*>(&xs[row][kq * 4]);
            acc = fmaf(xv.x, Wc[kq * 4 + 0], acc);
            acc = fmaf(xv.y, Wc[kq * 4 + 1], acc);
            acc = fmaf(xv.z, Wc[kq * 4 + 2], acc);
            acc = fmaf(xv.w, Wc[kq * 4 + 3], acc);
        }
        float vs = acc * asrc, vd = acc * adst;
#pragma unroll
        for (int off = 32; off; off >>= 1) {
            vs += __shfl_xor(vs, off, 64);
            vd += __shfl_xor(vd, off, 64);
        }
        if (lane == 0) { es[rowbase + row] = vs; ed[rowbase + row] = vd; }
        edm = fmaxf(edm, vd);
        u16 hi = f2bf(acc);
        float lo = acc - bf2f(hi);
        lh[lane][row] = hi;
        ll[lane][row] = f2bf(lo);
    }
    if (lane == 0) atomicMax(edmax + b, encf(edm));
    __syncthreads();

    {
        const int d = tid >> 2, part = tid & 3;
        u32 h0 = lh[d][part*4+0] | ((u32)lh[d][part*4+1] << 16);
        u32 h1 = lh[d][part*4+2] | ((u32)lh[d][part*4+3] << 16);
        u32 l0 = ll[d][part*4+0] | ((u32)ll[d][part*4+1] << 16);
        u32 l1 = ll[d][part*4+2] | ((u32)ll[d][part*4+3] << 16);
        size_t goff = (size_t)(b * 64 + d) * 2048 + col0 + part * 4;
        *reinterpret_cast<uint2*>(hT_hi + goff) = make_uint2(h0, h1);
        *reinterpret_cast<uint2*>(hT_lo + goff) = make_uint2(l0, l1);
    }
}

// K3: block = 64 rows x 1024 j; 8 waves = 4 rg x 2 jq; 16 windows of 32 j.
// Adjacency streamed per-window straight into the consuming lane's registers;
// hT double-buffered in LDS; one barrier per window.
__global__ __launch_bounds__(512, 4) void gat_k3(
    const int* __restrict__ adj,
    const u16* __restrict__ hT_hi, const u16* __restrict__ hT_lo,
    const float* __restrict__ es, const float* __restrict__ ed,
    const u32* __restrict__ edmax,
    float* __restrict__ acc_part, float* __restrict__ rs_part)
{
    __shared__ char smem[SMEM_SZ] __attribute__((aligned(16)));
    const int g = blockIdx.x;
    const int b     = g & 7;              // batch -> XCD pinned
    const int t2    = g >> 3;
    const int itile = t2 & 31;            // 32 row-tiles of 64
    const int jhalf = t2 >> 5;            // 2 j-halves of 1024
    const int tid  = threadIdx.x;
    const int lane = tid & 63;
    const int w    = tid >> 6;            // 0..7
    const int rg   = w & 3;               // row-group (16 rows)
    const int jq   = w >> 2;              // j-quarter (512 cols)
    const int li   = lane & 15;
    const int lg   = lane >> 4;
    const int cb   = jhalf * 1024;        // col base
    const int gr0  = b * 2048 + itile * 64;

    // ---- stage ed chunk; softmax constants ----
    {
        float* edL = (float*)(smem + EDL_OFF);
        edL[tid]       = ed[b * 2048 + cb + tid];
        edL[tid + 512] = ed[b * 2048 + cb + tid + 512];
    }
    const float es_i = es[gr0 + rg * 16 + li];
    const float edM  = decf(edmax[b]);
    const float t0   = es_i + edM;
    const float Mi   = fmaxf(t0, 0.2f * t0);      // exact upper bound on row max
    const float L2E  = 1.44269504088896f;
    const float CL   = Mi * L2E;

    // ---- per-lane adjacency stream base: this lane's 8 cols of its row ----
    const int* __restrict__ arow =
        adj + (size_t)(gr0 + rg * 16 + li) * 2048 + cb + jq * 512 + lg * 8;

    // ---- hT staging geometry (reg -> LDS) ----
    const int dd  = rg * 16 + (lane >> 2);        // d-row this lane stages
    const size_t gb = (size_t)(b * 64 + dd) * 2048 + cb + jq * 512 + (lane & 3) * 8;
    const int swoff = dd * ROWB + (lane & 3) * 16;

    char* slabA = smem + DBUF_OFF + jq * SLAB_SZ;            // buf 0
    char* slabB = smem + DBUF_OFF + (2 * SLAB_SZ) + jq * SLAB_SZ; // buf 1

    // ---- prologue: window 0 ----
    int4 ac0 = *reinterpret_cast<const int4*>(arow);
    int4 ac1 = *reinterpret_cast<const int4*>(arow + 4);
    {
        short8 svh = *reinterpret_cast<const short8*>(hT_hi + gb);
        short8 svl = *reinterpret_cast<const short8*>(hT_lo + gb);
        *reinterpret_cast<short8*>(slabA + swoff) = svh;
        *reinterpret_cast<short8*>(slabA + 5120 + swoff) = svl;
    }
    __syncthreads();

    f32x4 acc0 = {0.f,0.f,0.f,0.f}, acc1 = {0.f,0.f,0.f,0.f};
    f32x4 acc2 = {0.f,0.f,0.f,0.f}, acc3 = {0.f,0.f,0.f,0.f};
    float rs = 0.f;
    const float* edq = (const float*)(smem + EDL_OFF) + jq * 512 + lg * 8;
    const int fo = li * ROWB + lg * 16;

#pragma unroll 2
    for (int kk = 0; kk < 16; ++kk) {
        // prefetch next window (adj + hT) early — hides HBM/L2 latency
        int4 an0, an1; short8 svh, svl;
        if (kk < 15) {
            an0 = *reinterpret_cast<const int4*>(arow + (kk + 1) * 32);
            an1 = *reinterpret_cast<const int4*>(arow + (kk + 1) * 32 + 4);
            svh = *reinterpret_cast<const short8*>(hT_hi + gb + (kk + 1) * 32);
            svl = *reinterpret_cast<const short8*>(hT_lo + gb + (kk + 1) * 32);
        }

        const float4 e0 = *reinterpret_cast<const float4*>(edq + kk * 32);
        const float4 e1 = *reinterpret_cast<const float4*>(edq + kk * 32 + 4);
        const float ev[8] = {e0.x,e0.y,e0.z,e0.w,e1.x,e1.y,e1.z,e1.w};
        const int   av[8] = {ac0.x,ac0.y,ac0.z,ac0.w,ac1.x,ac1.y,ac1.z,ac1.w};

        float pe[8];
#pragma unroll
        for (int q = 0; q < 8; ++q) {
            const float tt = es_i + ev[q];
            const float eL = fmaxf(tt, 0.2f * tt);
            const float p  = __builtin_amdgcn_exp2f(fmaf(eL, L2E, -CL));
            pe[q] = av[q] ? p : 0.f;
        }
        rs += ((pe[0]+pe[1]) + (pe[2]+pe[3])) + ((pe[4]+pe[5]) + (pe[6]+pe[7]));

        short8 pa;
#pragma unroll
        for (int q = 0; q < 8; ++q) pa[q] = (short)f2bf(pe[q]);

        const char* slab = (kk & 1) ? slabB : slabA;
        short8 f0h = *reinterpret_cast<const short8*>(slab + fo);
        short8 f1h = *reinterpret_cast<const short8*>(slab + 16 * ROWB + fo);
        short8 f2h = *reinterpret_cast<const short8*>(slab + 32 * ROWB + fo);
        short8 f3h = *reinterpret_cast<const short8*>(slab + 48 * ROWB + fo);
        short8 f0l = *reinterpret_cast<const short8*>(slab + 5120 + fo);
        short8 f1l = *reinterpret_cast<const short8*>(slab + 5120 + 16 * ROWB + fo);
        short8 f2l = *reinterpret_cast<const short8*>(slab + 5120 + 32 * ROWB + fo);
        short8 f3l = *reinterpret_cast<const short8*>(slab + 5120 + 48 * ROWB + fo);

        acc0 = __builtin_amdgcn_mfma_f32_16x16x32_bf16(pa, f0h, acc0, 0, 0, 0);
        acc1 = __builtin_amdgcn_mfma_f32_16x16x32_bf16(pa, f1h, acc1, 0, 0, 0);
        acc2 = __builtin_amdgcn_mfma_f32_16x16x32_bf16(pa, f2h, acc2, 0, 0, 0);
        acc3 = __builtin_amdgcn_mfma_f32_16x16x32_bf16(pa, f3h, acc3, 0, 0, 0);
        acc0 = __builtin_amdgcn_mfma_f32_16x16x32_bf16(pa, f0l, acc0, 0, 0, 0);
        acc1 = __builtin_amdgcn_mfma_f32_16x16x32_bf16(pa, f1l, acc1, 0, 0, 0);
        acc2 = __builtin_amdgcn_mfma_f32_16x16x32_bf16(pa, f2l, acc2, 0, 0, 0);
        acc3 = __builtin_amdgcn_mfma_f32_16x16x32_bf16(pa, f3l, acc3, 0, 0, 0);

        if (kk < 15) {
            char* nslab = (kk & 1) ? slabA : slabB;   // WAR-safe: drained at prev barrier
            *reinterpret_cast<short8*>(nslab + swoff) = svh;
            *reinterpret_cast<short8*>(nslab + 5120 + swoff) = svl;
            ac0 = an0; ac1 = an1;
        }
        __syncthreads();
    }

    // ---- epilogue: jq-combine in LDS, write per-jhalf partials ----
    rs += __shfl_xor(rs, 16, 64);
    rs += __shfl_xor(rs, 32, 64);
    float* rsL = (float*)(smem + RSL_OFF);
    if (lane < 16) rsL[jq * 64 + rg * 16 + li] = rs;

    float* accL = (float*)(smem + DBUF_OFF);   // [w][16][64], aliases dbuf (drained)
    {
        f32x4 accs[4] = {acc0, acc1, acc2, acc3};
#pragma unroll
        for (int dt = 0; dt < 4; ++dt)
#pragma unroll
            for (int r = 0; r < 4; ++r)
                accL[(w * 16 + 4 * lg + r) * 64 + dt * 16 + li] = accs[dt][r];
    }
    __syncthreads();

    {
#pragma unroll
        for (int rep = 0; rep < 2; ++rep) {
            const int fi = (rep * 512 + tid) * 4;       // float idx 0..4095
            const int r  = fi >> 6;                     // row 0..63
            const int d0 = fi & 63;
            const int rgo = r >> 4, ri = r & 15;
            const float4 u0 = *reinterpret_cast<const float4*>(accL + ((0 + rgo) * 16 + ri) * 64 + d0);
            const float4 u1 = *reinterpret_cast<const float4*>(accL + ((4 + rgo) * 16 + ri) * 64 + d0);
            float4 o = make_float4(u0.x+u1.x, u0.y+u1.y, u0.z+u1.z, u0.w+u1.w);
            *reinterpret_cast<float4*>(acc_part + ((size_t)jhalf * 16384 + gr0 + r) * 64 + d0) = o;
        }
        if (tid < 64)
            rs_part[(size_t)jhalf * 16384 + gr0 + tid] = rsL[tid] + rsL[64 + tid];
    }
}

// K4: combine the two j-halves, normalize
__global__ __launch_bounds__(512) void gat_k4(
    const float4* __restrict__ ap, const float* __restrict__ rp,
    float4* __restrict__ out)
{
    const int idx = blockIdx.x * 512 + threadIdx.x;   // 0..262143 float4s
    const int row = idx >> 4;
    const float4 u0 = ap[idx];
    const float4 u1 = ap[262144 + idx];
    const float inv = 1.0f / (rp[row] + rp[16384 + row]);
    out[idx] = make_float4((u0.x+u1.x)*inv, (u0.y+u1.y)*inv,
                           (u0.z+u1.z)*inv, (u0.w+u1.w)*inv);
}

extern "C" void kernel_launch(void* const* d_in, const int* in_sizes, int n_in,
                              void* d_out, int out_size, void* d_ws, size_t ws_size,
                              hipStream_t stream)
{
    const float* x   = (const float*)d_in[0];
    const int*   adj = (const int*)d_in[1];
    const float* W   = (const float*)d_in[2];
    const float* a   = (const float*)d_in[3];
    float* out = (float*)d_out;

    char* ws = (char*)d_ws;
    size_t off = 0;
    auto carve = [&](size_t bytes) -> void* {
        void* p = ws + off;
        off += (bytes + 255) & ~(size_t)255;
        return p;
    };
    u16*   hT_hi    = (u16*)  carve((size_t)NB * 64 * NN * 2);
    u16*   hT_lo    = (u16*)  carve((size_t)NB * 64 * NN * 2);
    float* es       = (float*)carve((size_t)NB * NN * 4);
    float* ed       = (float*)carve((size_t)NB * NN * 4);
    u32*   edmax    = (u32*)  carve(256);
    float* acc_part = (float*)carve((size_t)2 * NB * NN * 64 * 4);  // 8 MB
    float* rs_part  = (float*)carve((size_t)2 * NB * NN * 4);       // 128 KB
    (void)ws_size; (void)in_sizes; (void)n_in; (void)out_size;

    hipMemsetAsync(edmax, 0, 256, stream);
    gat_k1<<<NB * NN / 16, 256, 0, stream>>>(x, W, a, hT_hi, hT_lo, es, ed, edmax);
    gat_k3<<<2 * NB * NN / 64, 512, 0, stream>>>(adj, hT_hi, hT_lo, es, ed, edmax,
                                                 acc_part, rs_part);
    gat_k4<<<512, 512, 0, stream>>>((const float4*)acc_part, rs_part, (float4*)out);
}